// Round 2
// 245.279 us; speedup vs baseline: 1.2523x; 1.2523x over previous
//
#include <hip/hip_runtime.h>
#include <math.h>

// TranAD fused forward: one block per batch element b (grid=128, 1024 thr).
// The whole 2-pass network is independent per b: attention mixes over l only,
// GEMMs are row-local, pass2's c=(x1-src)^2 is per (l,b). All activations in LDS.
//
// LDS regions (pitch 68 rows x 100 unless noted):
//   R0: s / mem (encoder stream, residuals)            6800 f
//   R1: q / attention-out / x1 (pitch 36) scratch      6800 f
//   R2: KV interleaved float4 [32 heads][101]          12928 f  (FFN hidden H overlaps)
//   R3: t (decoder stream)                             6800 f
//   RW: weight staging (transposed)                    4352 f
// total 37680 floats = 150720 B  -> 1 block/CU, 16 waves.

#define TPB 1024
#define SQ32 5.656854249492381f

#ifndef __has_builtin
#define __has_builtin(x) 0
#endif
#if __has_builtin(__builtin_amdgcn_exp2f)
#define EXP2(x) __builtin_amdgcn_exp2f(x)
#else
#define EXP2(x) exp2f(x)
#endif

struct KParams { const void* p[36]; };

// ---- stage weights transposed: Ws[k*(MC+4)+m] = W[m*K+k] ----
template<int K, int MC>
__device__ __forceinline__ void ldw(const float* __restrict__ Wt, float* __restrict__ Ws, int tid)
{
    constexpr int WP = MC + 4;
    for (int i = tid; i < MC * K; i += TPB) {
        int m = i / K, k = i - m * K;
        Ws[k * WP + m] = Wt[i];
    }
}

// ---- 1 row x 4 cols ----
template<int K, int WP>
__device__ __forceinline__ void gemm_row(const float* __restrict__ xrow,
                                         const float* __restrict__ wcol, float acc[4])
{
#pragma unroll 4
    for (int k = 0; k < K; ++k) {
        float xv = xrow[k];
        float4 w = *reinterpret_cast<const float4*>(wcol + k * WP);
        acc[0] = fmaf(xv, w.x, acc[0]);
        acc[1] = fmaf(xv, w.y, acc[1]);
        acc[2] = fmaf(xv, w.z, acc[2]);
        acc[3] = fmaf(xv, w.w, acc[3]);
    }
}

// ---- 2 rows (r0, r0+64) x 4 cols ----
template<int K, int XP, int WP>
__device__ __forceinline__ void gemm_dual(const float* __restrict__ Xs,
                                          const float* __restrict__ wcol,
                                          int r0, float a0[4], float a1[4])
{
    const float* x0 = Xs + r0 * XP;
    const float* x1 = x0 + 64 * XP;
#pragma unroll 4
    for (int k = 0; k < K; ++k) {
        float xa = x0[k], xb = x1[k];
        float4 w = *reinterpret_cast<const float4*>(wcol + k * WP);
        a0[0] = fmaf(xa, w.x, a0[0]); a0[1] = fmaf(xa, w.y, a0[1]);
        a0[2] = fmaf(xa, w.z, a0[2]); a0[3] = fmaf(xa, w.w, a0[3]);
        a1[0] = fmaf(xb, w.x, a1[0]); a1[1] = fmaf(xb, w.y, a1[1]);
        a1[2] = fmaf(xb, w.z, a1[2]); a1[3] = fmaf(xb, w.w, a1[3]);
    }
}

// route a 4-col result into q (R1) or interleaved KV (R2)
__device__ __forceinline__ void qkv_store(int mc, int l, int cg, const float4 bb,
                                          const float a[4], float* __restrict__ Q,
                                          float4* __restrict__ KV)
{
    if (mc == 0) {
        *reinterpret_cast<float4*>(Q + l * 68 + 4 * cg) =
            make_float4(a[0] + bb.x, a[1] + bb.y, a[2] + bb.z, a[3] + bb.w);
    } else {
        int h = 2 * cg;                       // cols 4cg..4cg+3 -> heads h, h+1
        float* p0 = reinterpret_cast<float*>(KV + h * 101 + l);
        float* p1 = reinterpret_cast<float*>(KV + (h + 1) * 101 + l);
        int off = (mc == 1) ? 0 : 2;          // k -> .xy, v -> .zw
        *reinterpret_cast<float2*>(p0 + off) = make_float2(a[0] + bb.x, a[1] + bb.y);
        *reinterpret_cast<float2*>(p1 + off) = make_float2(a[2] + bb.z, a[3] + bb.w);
    }
}

// one 64-col projection chunk: out = X @ W_chunk^T + b_chunk
__device__ __forceinline__ void proj_chunk(const float* __restrict__ Xs,
                                           const float* __restrict__ W,   // [64][64] rows
                                           const float* __restrict__ Bi,  // 64 (pre-offset)
                                           int mc, float* __restrict__ Q,
                                           float4* __restrict__ KV,
                                           float* __restrict__ RW, int tid)
{
    __syncthreads();                 // RW reuse + upstream X writes
    ldw<64, 64>(W, RW, tid);
    __syncthreads();
    const int r0 = tid >> 4, cg = tid & 15;
    const float* wcol = RW + 4 * cg;
    float4 bb = *reinterpret_cast<const float4*>(Bi + 4 * cg);
    if (r0 < 36) {
        float a0[4] = {0, 0, 0, 0}, a1[4] = {0, 0, 0, 0};
        gemm_dual<64, 68, 68>(Xs, wcol, r0, a0, a1);
        qkv_store(mc, r0, cg, bb, a0, Q, KV);
        qkv_store(mc, r0 + 64, cg, bb, a1, Q, KV);
    } else {
        float a0[4] = {0, 0, 0, 0};
        gemm_row<64, 68>(Xs + r0 * 68, wcol, a0);
        qkv_store(mc, r0, cg, bb, a0, Q, KV);
    }
}

// out-projection + residual, in place on Sres
__device__ __forceinline__ void proj_out_res(const float* __restrict__ Ain,
                                             const float* __restrict__ W,
                                             const float* __restrict__ Bi,
                                             float* __restrict__ Sres,
                                             float* __restrict__ RW, int tid)
{
    __syncthreads();
    ldw<64, 64>(W, RW, tid);
    __syncthreads();
    const int r0 = tid >> 4, cg = tid & 15;
    const float* wcol = RW + 4 * cg;
    float4 bb = *reinterpret_cast<const float4*>(Bi + 4 * cg);
    if (r0 < 36) {
        float a0[4] = {0, 0, 0, 0}, a1[4] = {0, 0, 0, 0};
        gemm_dual<64, 68, 68>(Ain, wcol, r0, a0, a1);
        float* sp0 = Sres + r0 * 68 + 4 * cg;
        float4 s0 = *reinterpret_cast<float4*>(sp0);
        *reinterpret_cast<float4*>(sp0) = make_float4(a0[0] + bb.x + s0.x, a0[1] + bb.y + s0.y,
                                                      a0[2] + bb.z + s0.z, a0[3] + bb.w + s0.w);
        float* sp1 = Sres + (r0 + 64) * 68 + 4 * cg;
        float4 s1 = *reinterpret_cast<float4*>(sp1);
        *reinterpret_cast<float4*>(sp1) = make_float4(a1[0] + bb.x + s1.x, a1[1] + bb.y + s1.y,
                                                      a1[2] + bb.z + s1.z, a1[3] + bb.w + s1.w);
    } else {
        float a0[4] = {0, 0, 0, 0};
        gemm_row<64, 68>(Ain + r0 * 68, wcol, a0);
        float* sp0 = Sres + r0 * 68 + 4 * cg;
        float4 s0 = *reinterpret_cast<float4*>(sp0);
        *reinterpret_cast<float4*>(sp0) = make_float4(a0[0] + bb.x + s0.x, a0[1] + bb.y + s0.y,
                                                      a0[2] + bb.z + s0.z, a0[3] + bb.w + s0.w);
    }
    __syncthreads();
}

// X += W2 @ (W1 @ X + b1) + b2   (LeakyReLU(True) == identity)
__device__ __forceinline__ void ffn_block(float* __restrict__ X,
                                          const float* __restrict__ W1, const float* __restrict__ B1,
                                          const float* __restrict__ W2, const float* __restrict__ B2,
                                          float* __restrict__ RW, float* __restrict__ H, int tid)
{
    __syncthreads();
    ldw<64, 16>(W1, RW, tid);
    __syncthreads();
    {
        const int r = tid >> 3, lp = tid & 7;
        if (r < 100) {
            float h0 = B1[2 * lp], h1 = B1[2 * lp + 1];
            const float* xrow = X + r * 68;
#pragma unroll 4
            for (int k = 0; k < 64; ++k) {
                float xv = xrow[k];
                h0 = fmaf(xv, RW[k * 20 + 2 * lp], h0);
                h1 = fmaf(xv, RW[k * 20 + 2 * lp + 1], h1);
            }
            H[r * 20 + 2 * lp] = h0;
            H[r * 20 + 2 * lp + 1] = h1;
        }
    }
    __syncthreads();
    ldw<16, 64>(W2, RW, tid);
    __syncthreads();
    const int r0 = tid >> 4, cg = tid & 15;
    const float* wcol = RW + 4 * cg;
    float4 bb = *reinterpret_cast<const float4*>(B2 + 4 * cg);
    if (r0 < 36) {
        float a0[4] = {0, 0, 0, 0}, a1[4] = {0, 0, 0, 0};
        gemm_dual<16, 20, 68>(H, wcol, r0, a0, a1);
        float* xp0 = X + r0 * 68 + 4 * cg;
        float4 u0 = *reinterpret_cast<float4*>(xp0);
        *reinterpret_cast<float4*>(xp0) = make_float4(a0[0] + bb.x + u0.x, a0[1] + bb.y + u0.y,
                                                      a0[2] + bb.z + u0.z, a0[3] + bb.w + u0.w);
        float* xp1 = X + (r0 + 64) * 68 + 4 * cg;
        float4 u1 = *reinterpret_cast<float4*>(xp1);
        *reinterpret_cast<float4*>(xp1) = make_float4(a1[0] + bb.x + u1.x, a1[1] + bb.y + u1.y,
                                                      a1[2] + bb.z + u1.z, a1[3] + bb.w + u1.w);
    } else {
        float a0[4] = {0, 0, 0, 0};
        gemm_row<16, 68>(H + r0 * 20, wcol, a0);   // FIX: weight pitch is 68 (was 20)
        float* xp0 = X + r0 * 68 + 4 * cg;
        float4 u0 = *reinterpret_cast<float4*>(xp0);
        *reinterpret_cast<float4*>(xp0) = make_float4(a0[0] + bb.x + u0.x, a0[1] + bb.y + u0.y,
                                                      a0[2] + bb.z + u0.z, a0[3] + bb.w + u0.w);
    }
    __syncthreads();
}

// attention over 32 heads x 100 queries; head_dim=2. Task = (head, 4-query group)
// so each KV ds_read_b128 is amortized over 4 queries (4x less LDS traffic).
// exp via native v_exp_f32: log2e * (1/sqrt(2)) folded into q.
__device__ __forceinline__ void attn_block(float* __restrict__ Q,
                                           const float4* __restrict__ KV, int tid)
{
    __syncthreads();
    if (tid < 800) {
        const int h = tid / 25;
        const int g = tid - h * 25;
        const float4* kv = KV + h * 101;
        const int lq0 = 4 * g;
        const float SCALE = 0.7071067811865476f * 1.4426950408889634f;
        float q0[4], q1[4];
#pragma unroll
        for (int j = 0; j < 4; ++j) {
            float2 qv = *reinterpret_cast<const float2*>(Q + (lq0 + j) * 68 + 2 * h);
            q0[j] = qv.x * SCALE;
            q1[j] = qv.y * SCALE;
        }
        float mx[4] = {-1e30f, -1e30f, -1e30f, -1e30f};
#pragma unroll 4
        for (int s = 0; s < 100; ++s) {
            float4 k = kv[s];
#pragma unroll
            for (int j = 0; j < 4; ++j)
                mx[j] = fmaxf(mx[j], fmaf(q0[j], k.x, q1[j] * k.y));
        }
        float sum[4] = {0, 0, 0, 0}, a0[4] = {0, 0, 0, 0}, a1[4] = {0, 0, 0, 0};
#pragma unroll 4
        for (int s = 0; s < 100; ++s) {
            float4 k = kv[s];
#pragma unroll
            for (int j = 0; j < 4; ++j) {
                float e = EXP2(fmaf(q0[j], k.x, fmaf(q1[j], k.y, -mx[j])));
                sum[j] += e;
                a0[j] = fmaf(e, k.z, a0[j]);
                a1[j] = fmaf(e, k.w, a1[j]);
            }
        }
#pragma unroll
        for (int j = 0; j < 4; ++j) {
            float inv = 1.f / sum[j];
            *reinterpret_cast<float2*>(Q + (lq0 + j) * 68 + 2 * h) =
                make_float2(a0[j] * inv, a1[j] * inv);
        }
    }
    __syncthreads();
}

// ---------------------------------------------------------------------------
__global__ __launch_bounds__(1024) void k_fused(KParams prm, float* __restrict__ outp)
{
    __shared__ float R0[6800];
    __shared__ float R1[6800];
    __shared__ float4 R2[3232];
    __shared__ float R3[6800];
    __shared__ float RW[64 * 68];

    const int tid = threadIdx.x;
    const int b = blockIdx.x;
    const float* src = (const float*)prm.p[0];
    const float* tgt = (const float*)prm.p[1];

    for (int pass = 0; pass < 2; ++pass) {
        const float* Weq  = (const float*)prm.p[2];
        const float* Beq  = (const float*)prm.p[3];
        const float* Weo  = (const float*)prm.p[4];
        const float* Beo  = (const float*)prm.p[5];
        const float* Wel1 = (const float*)prm.p[22];
        const float* Bel1 = (const float*)prm.p[23];
        const float* Wel2 = (const float*)prm.p[24];
        const float* Bel2 = (const float*)prm.p[25];
        const float* Wsa  = (const float*)prm.p[pass ? 14 : 6];
        const float* Bsa  = (const float*)prm.p[pass ? 15 : 7];
        const float* Wsao = (const float*)prm.p[pass ? 16 : 8];
        const float* Bsao = (const float*)prm.p[pass ? 17 : 9];
        const float* Wca  = (const float*)prm.p[pass ? 18 : 10];
        const float* Bca  = (const float*)prm.p[pass ? 19 : 11];
        const float* Wcao = (const float*)prm.p[pass ? 20 : 12];
        const float* Bcao = (const float*)prm.p[pass ? 21 : 13];
        const float* Wdl1 = (const float*)prm.p[pass ? 30 : 26];
        const float* Bdl1 = (const float*)prm.p[pass ? 31 : 27];
        const float* Wdl2 = (const float*)prm.p[pass ? 32 : 28];
        const float* Bdl2 = (const float*)prm.p[pass ? 33 : 29];
        const float* Wf   = (const float*)prm.p[34];
        const float* Bf   = (const float*)prm.p[35];
        float* outx = outp + (pass ? 409600 : 0);

        // ---- stage 1: s = concat(src, c)*sqrt(32) + pe  -> R0
        // pass0: c = 0; pass1: c = (x1 - src)^2 with x1 in R1 (pitch 36)
        __syncthreads();   // guards previous pass's R1 (x1) write / R0 (mem) last read
        for (int i = tid; i < 6400; i += TPB) {
            int l = i >> 6, d = i & 63;
            float sv = src[(size_t)(l * 128 + b) * 32 + (d & 31)];
            float v;
            if (d < 32) v = sv;
            else if (pass == 0) v = 0.f;
            else { float df = R1[l * 36 + (d - 32)] - sv; v = df * df; }
            float div = __expf((float)d * -0.14391156831212787f);
            float ang = (float)l * div;
            R0[l * 68 + d] = v * SQ32 + (sinf(ang) + cosf(ang));
        }

        // ---- encoder: self-attn + FFN on R0 (becomes mem) ----
        for (int mc = 0; mc < 3; ++mc)
            proj_chunk(R0, Weq + mc * 4096, Beq + mc * 64, mc, R1, R2, RW, tid);
        attn_block(R1, R2, tid);
        proj_out_res(R1, Weo, Beo, R0, RW, tid);
        ffn_block(R0, Wel1, Bel1, Wel2, Bel2, RW, (float*)R2, tid);

        // ---- t = tile(tgt) -> R3
        for (int i = tid; i < 800; i += TPB) {
            int l = i >> 3, q4 = i & 7;
            float4 tv = *reinterpret_cast<const float4*>(tgt + (size_t)(l * 128 + b) * 32 + 4 * q4);
            *reinterpret_cast<float4*>(R3 + l * 68 + 4 * q4) = tv;
            *reinterpret_cast<float4*>(R3 + l * 68 + 32 + 4 * q4) = tv;
        }

        // ---- decoder self-attention ----
        for (int mc = 0; mc < 3; ++mc)
            proj_chunk(R3, Wsa + mc * 4096, Bsa + mc * 64, mc, R1, R2, RW, tid);
        attn_block(R1, R2, tid);
        proj_out_res(R1, Wsao, Bsao, R3, RW, tid);

        // ---- decoder cross-attention: q from t (R3), kv from mem (R0) ----
        proj_chunk(R3, Wca, Bca, 0, R1, R2, RW, tid);
        proj_chunk(R0, Wca + 4096, Bca + 64, 1, R1, R2, RW, tid);
        proj_chunk(R0, Wca + 8192, Bca + 128, 2, R1, R2, RW, tid);
        attn_block(R1, R2, tid);
        proj_out_res(R1, Wcao, Bcao, R3, RW, tid);
        ffn_block(R3, Wdl1, Bdl1, Wdl2, Bdl2, RW, (float*)R2, tid);

        // ---- head: x = sigmoid(R3 @ Wf^T + bf) -> out (and R1 for pass2's c) ----
        __syncthreads();
        ldw<64, 32>(Wf, RW, tid);
        __syncthreads();
        {
            const int r = tid >> 3, lp = tid & 7;
            if (r < 100) {
                float a[4] = {0, 0, 0, 0};
                gemm_row<64, 36>(R3 + r * 68, RW + 4 * lp, a);
                float4 bb = *reinterpret_cast<const float4*>(Bf + 4 * lp);
                float o0 = 1.f / (1.f + __expf(-(a[0] + bb.x)));
                float o1 = 1.f / (1.f + __expf(-(a[1] + bb.y)));
                float o2 = 1.f / (1.f + __expf(-(a[2] + bb.z)));
                float o3 = 1.f / (1.f + __expf(-(a[3] + bb.w)));
                *reinterpret_cast<float4*>(outx + (size_t)(r * 128 + b) * 32 + 4 * lp) =
                    make_float4(o0, o1, o2, o3);
                if (pass == 0)
                    *reinterpret_cast<float4*>(R1 + r * 36 + 4 * lp) =
                        make_float4(o0, o1, o2, o3);
            }
        }
    }
}

// ---------------------------------------------------------------------------
extern "C" void kernel_launch(void* const* d_in, const int* in_sizes, int n_in,
                              void* d_out, int out_size, void* d_ws, size_t ws_size,
                              hipStream_t stream)
{
    KParams prm;
    for (int i = 0; i < 36; ++i) prm.p[i] = d_in[i];
    k_fused<<<dim3(128), dim3(1024), 0, stream>>>(prm, (float*)d_out);
}